// Round 1
// baseline (761.157 us; speedup 1.0000x reference)
//
#include <hip/hip_runtime.h>
#include <hip/hip_bf16.h>

typedef unsigned short u16;
typedef __attribute__((ext_vector_type(8))) short short8;
typedef __attribute__((ext_vector_type(4))) float f32x4;

static __device__ __forceinline__ u16 f2bf(float f) {
    union { float f; unsigned u; } a; a.f = f;
    unsigned u = a.u;
    u += 0x7FFFu + ((u >> 16) & 1u);   // RNE; inputs are finite
    return (u16)(u >> 16);
}

// ---------------- Kernel 1: GroupNorm statistics (mu, rstd) per (b, g) ----------------
__global__ __launch_bounds__(256) void k_gnstats(const float* __restrict__ x, float* __restrict__ stats) {
    const int bg = blockIdx.x;                       // b*8 + g, 32 blocks
    const float* p = x + (size_t)bg * (32 * 4096);   // contiguous 131072 floats
    const int t = threadIdx.x;
    float s = 0.f, ss = 0.f;
    for (int i = t * 4; i < 32 * 4096; i += 256 * 4) {
        float4 v = *reinterpret_cast<const float4*>(p + i);
        s  += v.x + v.y + v.z + v.w;
        ss += v.x * v.x + v.y * v.y + v.z * v.z + v.w * v.w;
    }
    for (int off = 1; off < 64; off <<= 1) { s += __shfl_xor(s, off); ss += __shfl_xor(ss, off); }
    __shared__ float ls[4], lss[4];
    if ((t & 63) == 0) { ls[t >> 6] = s; lss[t >> 6] = ss; }
    __syncthreads();
    if (t == 0) {
        float S  = ls[0] + ls[1] + ls[2] + ls[3];
        float SS = lss[0] + lss[1] + lss[2] + lss[3];
        const float inv = 1.f / (32.f * 4096.f);
        float mu  = S * inv;
        float var = SS * inv - mu * mu;
        stats[bg * 2]     = mu;
        stats[bg * 2 + 1] = rsqrtf(var + 1e-5f);
    }
}

// ---------------- Kernel 2: fused GN-normalize + QKV 1x1 conv (fp32 GEMM) ----------------
// out[b][o][n] = sum_c qkv_w[o][c] * h[b][c][n] + qkv_b[o]
// Writes: Q (B,N,C) bf16 pre-scaled by 1/16 ; K (B,N,C) bf16 ; V (B,C,N) bf16
__global__ __launch_bounds__(256) void k_qkv(const float* __restrict__ x, const float* __restrict__ gamma,
                                             const float* __restrict__ beta, const float* __restrict__ qkv_w,
                                             const float* __restrict__ qkv_b, const float* __restrict__ stats,
                                             u16* __restrict__ Q, u16* __restrict__ K, u16* __restrict__ V) {
    __shared__ float WT[32][72];   // W tile, transposed: [k][o_local]
    __shared__ float Hs[32][68];   // H tile: [k][n_local]
    __shared__ u16   T[64][72];    // epilogue staging (bf16)
    const int b = blockIdx.z, o0 = blockIdx.y * 64, n0 = blockIdx.x * 64;
    const int t = threadIdx.x, tx = t & 15, ty = t >> 4;
    const int sr = t >> 2, skb = (t & 3) * 8;   // W staging: row 0..63, k-base
    const int hk = t >> 3, hn = (t & 7) * 8;    // H staging: k 0..31, n-base

    float acc[4][4] = {};
    for (int kc = 0; kc < 256; kc += 32) {
        // stage W transposed
        const float* wp = &qkv_w[(size_t)(o0 + sr) * 256 + kc + skb];
        float4 w0 = *reinterpret_cast<const float4*>(wp);
        float4 w1 = *reinterpret_cast<const float4*>(wp + 4);
        WT[skb + 0][sr] = w0.x; WT[skb + 1][sr] = w0.y; WT[skb + 2][sr] = w0.z; WT[skb + 3][sr] = w0.w;
        WT[skb + 4][sr] = w1.x; WT[skb + 5][sr] = w1.y; WT[skb + 6][sr] = w1.z; WT[skb + 7][sr] = w1.w;
        // stage normalized H
        const int c = kc + hk;
        const float mu = stats[(b * 8 + (c >> 5)) * 2];
        const float rstd = stats[(b * 8 + (c >> 5)) * 2 + 1];
        const float ga = gamma[c] * rstd;
        const float be = beta[c] - mu * ga;
        const float* xp = &x[((size_t)b * 256 + c) * 4096 + n0 + hn];
        float4 h0 = *reinterpret_cast<const float4*>(xp);
        float4 h1 = *reinterpret_cast<const float4*>(xp + 4);
        h0.x = h0.x * ga + be; h0.y = h0.y * ga + be; h0.z = h0.z * ga + be; h0.w = h0.w * ga + be;
        h1.x = h1.x * ga + be; h1.y = h1.y * ga + be; h1.z = h1.z * ga + be; h1.w = h1.w * ga + be;
        *reinterpret_cast<float4*>(&Hs[hk][hn])     = h0;
        *reinterpret_cast<float4*>(&Hs[hk][hn + 4]) = h1;
        __syncthreads();
#pragma unroll
        for (int k = 0; k < 32; ++k) {
            const f32x4 av = *reinterpret_cast<const f32x4*>(&Hs[k][ty * 4]);  // n dim
            const f32x4 bv = *reinterpret_cast<const f32x4*>(&WT[k][tx * 4]);  // o dim
#pragma unroll
            for (int i = 0; i < 4; ++i)
#pragma unroll
                for (int j = 0; j < 4; ++j) acc[i][j] += av[i] * bv[j];
        }
        __syncthreads();
    }
    // epilogue: bias, scale (Q only), stage bf16 in LDS, coalesced global writes
    const bool isV = (o0 >= 512);
    const float scal = (o0 < 256) ? 0.0625f : 1.0f;  // fold attention scale C^-0.5 into Q
#pragma unroll
    for (int i = 0; i < 4; ++i)
#pragma unroll
        for (int j = 0; j < 4; ++j) {
            float val = (acc[i][j] + qkv_b[o0 + tx * 4 + j]) * scal;
            if (!isV) T[ty * 4 + i][tx * 4 + j] = f2bf(val);   // [n_local][ch_local]
            else      T[tx * 4 + j][ty * 4 + i] = f2bf(val);   // [ch_local][n_local]
        }
    __syncthreads();
    const int rr = t >> 2, cb = (t & 3) * 16;
    short8 s0 = *reinterpret_cast<short8*>(&T[rr][cb]);
    short8 s1 = *reinterpret_cast<short8*>(&T[rr][cb + 8]);
    u16* dst;
    if (o0 < 256)      dst = &Q[((size_t)b * 4096 + n0 + rr) * 256 + o0 + cb];
    else if (o0 < 512) dst = &K[((size_t)b * 4096 + n0 + rr) * 256 + (o0 - 256) + cb];
    else               dst = &V[((size_t)b * 256 + (o0 - 512) + rr) * 4096 + n0 + cb];
    *reinterpret_cast<short8*>(dst)     = s0;
    *reinterpret_cast<short8*>(dst + 8) = s1;
}

// ---------------- Kernel 3: flash attention, bf16 MFMA 16x16x32 ----------------
// Block = 128 threads = 2 independent waves; wave owns 32 q-rows, sweeps 64-key tiles.
// Q pre-scaled by 1/16. K/V fragments loaded straight from global (L2/L3-resident).
__global__ __launch_bounds__(128, 1) void k_flash(const u16* __restrict__ Qw, const u16* __restrict__ Kw,
                                                  const u16* __restrict__ Vw, float* __restrict__ Ow) {
    __shared__ u16 Ps[2][32][72];   // per-wave P transpose staging
    const int b = blockIdx.y;
    const int w = threadIdx.x >> 6;
    const int l = threadIdx.x & 63;
    const int lr = l & 15;          // row/col within 16
    const int lg = l >> 4;          // k-group
    const int qbase = blockIdx.x * 64 + w * 32;
    const size_t bN = (size_t)b * 4096;

    short8 qf[2][8];                // A-fragments of Q: [m-subtile][c-chunk]
#pragma unroll
    for (int m = 0; m < 2; ++m)
#pragma unroll
        for (int cc = 0; cc < 8; ++cc)
            qf[m][cc] = *reinterpret_cast<const short8*>(&Qw[(bN + qbase + m * 16 + lr) * 256 + cc * 32 + lg * 8]);

    f32x4 Oa[2][16];
    float mr[2][4], lsum[2][4];
#pragma unroll
    for (int m = 0; m < 2; ++m) {
#pragma unroll
        for (int cs = 0; cs < 16; ++cs) Oa[m][cs] = f32x4{0.f, 0.f, 0.f, 0.f};
#pragma unroll
        for (int i = 0; i < 4; ++i) { mr[m][i] = -1e30f; lsum[m][i] = 0.f; }
    }

    for (int kt = 0; kt < 64; ++kt) {
        const int kb = kt * 64;
        f32x4 s[2][4];
#pragma unroll
        for (int m = 0; m < 2; ++m)
#pragma unroll
            for (int n = 0; n < 4; ++n) s[m][n] = f32x4{0.f, 0.f, 0.f, 0.f};
        // S = Q K^T  (scores already scaled via Q)
#pragma unroll
        for (int cc = 0; cc < 8; ++cc) {
#pragma unroll
            for (int n = 0; n < 4; ++n) {
                short8 kf = *reinterpret_cast<const short8*>(&Kw[(bN + kb + n * 16 + lr) * 256 + cc * 32 + lg * 8]);
                s[0][n] = __builtin_amdgcn_mfma_f32_16x16x32_bf16(qf[0][cc], kf, s[0][n], 0, 0, 0);
                s[1][n] = __builtin_amdgcn_mfma_f32_16x16x32_bf16(qf[1][cc], kf, s[1][n], 0, 0, 0);
            }
        }
        // online softmax; D-layout: reg i of lane l -> row (l>>4)*4+i, col l&15
        float tmax[2][4];
        bool need = false;
#pragma unroll
        for (int m = 0; m < 2; ++m)
#pragma unroll
            for (int i = 0; i < 4; ++i) {
                float tm = fmaxf(fmaxf(s[m][0][i], s[m][1][i]), fmaxf(s[m][2][i], s[m][3][i]));
                tm = fmaxf(tm, __shfl_xor(tm, 1));
                tm = fmaxf(tm, __shfl_xor(tm, 2));
                tm = fmaxf(tm, __shfl_xor(tm, 4));
                tm = fmaxf(tm, __shfl_xor(tm, 8));
                tmax[m][i] = tm;
                need = need || (tm > mr[m][i]);
            }
        if (__any(need)) {   // exact: skip rescale when running max unchanged (alpha==1)
#pragma unroll
            for (int m = 0; m < 2; ++m) {
                f32x4 al;
#pragma unroll
                for (int i = 0; i < 4; ++i) {
                    float mn = fmaxf(mr[m][i], tmax[m][i]);
                    al[i] = __expf(mr[m][i] - mn);
                    mr[m][i] = mn;
                    lsum[m][i] *= al[i];
                }
#pragma unroll
                for (int cs = 0; cs < 16; ++cs) Oa[m][cs] *= al;
            }
        }
        // P = exp(S - m), accumulate per-lane partial row sums, stage P (bf16) for transpose
#pragma unroll
        for (int m = 0; m < 2; ++m)
#pragma unroll
            for (int n = 0; n < 4; ++n)
#pragma unroll
                for (int i = 0; i < 4; ++i) {
                    float p = __expf(s[m][n][i] - mr[m][i]);
                    lsum[m][i] += p;
                    Ps[w][m * 16 + lg * 4 + i][n * 16 + lr] = f2bf(p);
                }
        __syncthreads();
        short8 pf[2][2];
#pragma unroll
        for (int m = 0; m < 2; ++m)
#pragma unroll
            for (int kk = 0; kk < 2; ++kk)
                pf[m][kk] = *reinterpret_cast<const short8*>(&Ps[w][m * 16 + lr][kk * 32 + lg * 8]);
        // O += P V
#pragma unroll
        for (int cs = 0; cs < 16; ++cs) {
#pragma unroll
            for (int kk = 0; kk < 2; ++kk) {
                short8 vf = *reinterpret_cast<const short8*>(
                    &Vw[((size_t)b * 256 + cs * 16 + lr) * 4096 + kb + kk * 32 + lg * 8]);
                Oa[0][cs] = __builtin_amdgcn_mfma_f32_16x16x32_bf16(pf[0][kk], vf, Oa[0][cs], 0, 0, 0);
                Oa[1][cs] = __builtin_amdgcn_mfma_f32_16x16x32_bf16(pf[1][kk], vf, Oa[1][cs], 0, 0, 0);
            }
        }
    }
    // normalize and write O (B,N,C) fp32
    float linv[2][4];
#pragma unroll
    for (int m = 0; m < 2; ++m)
#pragma unroll
        for (int i = 0; i < 4; ++i) {
            float tsum = lsum[m][i];
            tsum += __shfl_xor(tsum, 1);
            tsum += __shfl_xor(tsum, 2);
            tsum += __shfl_xor(tsum, 4);
            tsum += __shfl_xor(tsum, 8);
            linv[m][i] = 1.f / tsum;
        }
#pragma unroll
    for (int m = 0; m < 2; ++m)
#pragma unroll
        for (int cs = 0; cs < 16; ++cs)
#pragma unroll
            for (int i = 0; i < 4; ++i)
                Ow[(bN + qbase + m * 16 + lg * 4 + i) * 256 + cs * 16 + lr] = Oa[m][cs][i] * linv[m][i];
}

// ---------------- Kernel 4: proj 1x1 conv + bias + residual (fp32 GEMM) ----------------
// out[b][c][n] = x[b][c][n] + proj_b[c] + sum_k proj_w[c][k] * O[b][n][k]
__global__ __launch_bounds__(256) void k_proj(const float* __restrict__ Ow, const float* __restrict__ proj_w,
                                              const float* __restrict__ proj_b, const float* __restrict__ x,
                                              float* __restrict__ out) {
    __shared__ float WpT[32][72];   // [k][c_local]
    __shared__ float OT[32][72];    // [k][n_local]
    __shared__ float T3[64][68];    // [c_local][n_local]
    const int b = blockIdx.z, c0 = blockIdx.y * 64, n0 = blockIdx.x * 64;
    const int t = threadIdx.x, tx = t & 15, ty = t >> 4;
    const int sr = t >> 2, skb = (t & 3) * 8;

    float acc[4][4] = {};
    for (int kc = 0; kc < 256; kc += 32) {
        const float* wp = &proj_w[(size_t)(c0 + sr) * 256 + kc + skb];
        float4 w0 = *reinterpret_cast<const float4*>(wp);
        float4 w1 = *reinterpret_cast<const float4*>(wp + 4);
        WpT[skb + 0][sr] = w0.x; WpT[skb + 1][sr] = w0.y; WpT[skb + 2][sr] = w0.z; WpT[skb + 3][sr] = w0.w;
        WpT[skb + 4][sr] = w1.x; WpT[skb + 5][sr] = w1.y; WpT[skb + 6][sr] = w1.z; WpT[skb + 7][sr] = w1.w;
        const float* op = &Ow[((size_t)b * 4096 + n0 + sr) * 256 + kc + skb];
        float4 o0v = *reinterpret_cast<const float4*>(op);
        float4 o1v = *reinterpret_cast<const float4*>(op + 4);
        OT[skb + 0][sr] = o0v.x; OT[skb + 1][sr] = o0v.y; OT[skb + 2][sr] = o0v.z; OT[skb + 3][sr] = o0v.w;
        OT[skb + 4][sr] = o1v.x; OT[skb + 5][sr] = o1v.y; OT[skb + 6][sr] = o1v.z; OT[skb + 7][sr] = o1v.w;
        __syncthreads();
#pragma unroll
        for (int k = 0; k < 32; ++k) {
            const f32x4 av = *reinterpret_cast<const f32x4*>(&WpT[k][ty * 4]);  // c dim
            const f32x4 bv = *reinterpret_cast<const f32x4*>(&OT[k][tx * 4]);   // n dim
#pragma unroll
            for (int i = 0; i < 4; ++i)
#pragma unroll
                for (int j = 0; j < 4; ++j) acc[i][j] += av[i] * bv[j];
        }
        __syncthreads();
    }
#pragma unroll
    for (int i = 0; i < 4; ++i)
#pragma unroll
        for (int j = 0; j < 4; ++j) T3[ty * 4 + i][tx * 4 + j] = acc[i][j];
    __syncthreads();
    const int cl = t >> 2, nb = (t & 3) * 16;
    const float pb = proj_b[c0 + cl];
    const size_t base = ((size_t)b * 256 + c0 + cl) * 4096 + n0 + nb;
#pragma unroll
    for (int q = 0; q < 16; q += 4) {
        float4 xv = *reinterpret_cast<const float4*>(&x[base + q]);
        float4 tv = *reinterpret_cast<float4*>(&T3[cl][nb + q]);
        float4 r;
        r.x = xv.x + tv.x + pb; r.y = xv.y + tv.y + pb;
        r.z = xv.z + tv.z + pb; r.w = xv.w + tv.w + pb;
        *reinterpret_cast<float4*>(&out[base + q]) = r;
    }
}

extern "C" void kernel_launch(void* const* d_in, const int* in_sizes, int n_in,
                              void* d_out, int out_size, void* d_ws, size_t ws_size,
                              hipStream_t stream) {
    const float* x      = (const float*)d_in[0];
    const float* gngam  = (const float*)d_in[1];
    const float* gnbeta = (const float*)d_in[2];
    const float* qkv_w  = (const float*)d_in[3];
    const float* qkv_b  = (const float*)d_in[4];
    const float* proj_w = (const float*)d_in[5];
    const float* proj_b = (const float*)d_in[6];
    float* out = (float*)d_out;

    char* wsb = (char*)d_ws;
    float* stats = (float*)wsb;                                   // 64 floats
    u16* Qws = (u16*)(wsb + 1024);                                // (B,N,C) bf16, pre-scaled
    u16* Kws = Qws + (size_t)4 * 4096 * 256;                      // (B,N,C) bf16
    u16* Vws = Kws + (size_t)4 * 4096 * 256;                      // (B,C,N) bf16
    float* Ows = (float*)(wsb + 1024 + 3ull * 4 * 4096 * 256 * 2); // (B,N,C) fp32

    k_gnstats<<<32, 256, 0, stream>>>(x, stats);
    k_qkv<<<dim3(64, 12, 4), 256, 0, stream>>>(x, gngam, gnbeta, qkv_w, qkv_b, stats, Qws, Kws, Vws);
    k_flash<<<dim3(64, 4), 128, 0, stream>>>(Qws, Kws, Vws, Ows);
    k_proj<<<dim3(64, 4, 4), 256, 0, stream>>>(Ows, proj_w, proj_b, x, out);
}

// Round 2
// 316.586 us; speedup vs baseline: 2.4043x; 2.4043x over previous
//
#include <hip/hip_runtime.h>
#include <hip/hip_bf16.h>

typedef unsigned short u16;
typedef unsigned int u32;
typedef __attribute__((ext_vector_type(8))) short short8;
typedef __attribute__((ext_vector_type(4))) float f32x4;

static __device__ __forceinline__ u16 f2bf(float f) {
    union { float f; unsigned u; } a; a.f = f;
    unsigned u = a.u;
    u += 0x7FFFu + ((u >> 16) & 1u);   // RNE; inputs are finite
    return (u16)(u >> 16);
}
static __device__ __forceinline__ float bf2f(u16 h) {
    union { u32 u; float f; } a; a.u = ((u32)h) << 16; return a.f;
}
static __device__ __forceinline__ void gload16(const u16* g, u16* l) {
    __builtin_amdgcn_global_load_lds((const __attribute__((address_space(1))) u32*)(const void*)g,
                                     (__attribute__((address_space(3))) u32*)(void*)l, 16, 0, 0);
}

// ---------------- Kernel 1: GroupNorm statistics (mu, rstd) per (b, g) ----------------
__global__ __launch_bounds__(256) void k_gnstats(const float* __restrict__ x, float* __restrict__ stats) {
    const int bg = blockIdx.x;
    const float* p = x + (size_t)bg * (32 * 4096);
    const int t = threadIdx.x;
    float s = 0.f, ss = 0.f;
    for (int i = t * 4; i < 32 * 4096; i += 256 * 4) {
        float4 v = *reinterpret_cast<const float4*>(p + i);
        s  += v.x + v.y + v.z + v.w;
        ss += v.x * v.x + v.y * v.y + v.z * v.z + v.w * v.w;
    }
    for (int off = 1; off < 64; off <<= 1) { s += __shfl_xor(s, off); ss += __shfl_xor(ss, off); }
    __shared__ float ls[4], lss[4];
    if ((t & 63) == 0) { ls[t >> 6] = s; lss[t >> 6] = ss; }
    __syncthreads();
    if (t == 0) {
        float S  = ls[0] + ls[1] + ls[2] + ls[3];
        float SS = lss[0] + lss[1] + lss[2] + lss[3];
        const float inv = 1.f / (32.f * 4096.f);
        float mu  = S * inv;
        float var = SS * inv - mu * mu;
        stats[bg * 2]     = mu;
        stats[bg * 2 + 1] = rsqrtf(var + 1e-5f);
    }
}

// ---------------- Kernel 2: fused GN-normalize + QKV 1x1 conv (fp32 GEMM) ----------------
__global__ __launch_bounds__(256) void k_qkv(const float* __restrict__ x, const float* __restrict__ gamma,
                                             const float* __restrict__ beta, const float* __restrict__ qkv_w,
                                             const float* __restrict__ qkv_b, const float* __restrict__ stats,
                                             u16* __restrict__ Q, u16* __restrict__ K, u16* __restrict__ V) {
    __shared__ float WT[32][72];
    __shared__ float Hs[32][68];
    __shared__ u16   T[64][72];
    const int b = blockIdx.z, o0 = blockIdx.y * 64, n0 = blockIdx.x * 64;
    const int t = threadIdx.x, tx = t & 15, ty = t >> 4;
    const int sr = t >> 2, skb = (t & 3) * 8;
    const int hk = t >> 3, hn = (t & 7) * 8;

    float acc[4][4] = {};
    for (int kc = 0; kc < 256; kc += 32) {
        const float* wp = &qkv_w[(size_t)(o0 + sr) * 256 + kc + skb];
        float4 w0 = *reinterpret_cast<const float4*>(wp);
        float4 w1 = *reinterpret_cast<const float4*>(wp + 4);
        WT[skb + 0][sr] = w0.x; WT[skb + 1][sr] = w0.y; WT[skb + 2][sr] = w0.z; WT[skb + 3][sr] = w0.w;
        WT[skb + 4][sr] = w1.x; WT[skb + 5][sr] = w1.y; WT[skb + 6][sr] = w1.z; WT[skb + 7][sr] = w1.w;
        const int c = kc + hk;
        const float mu = stats[(b * 8 + (c >> 5)) * 2];
        const float rstd = stats[(b * 8 + (c >> 5)) * 2 + 1];
        const float ga = gamma[c] * rstd;
        const float be = beta[c] - mu * ga;
        const float* xp = &x[((size_t)b * 256 + c) * 4096 + n0 + hn];
        float4 h0 = *reinterpret_cast<const float4*>(xp);
        float4 h1 = *reinterpret_cast<const float4*>(xp + 4);
        h0.x = h0.x * ga + be; h0.y = h0.y * ga + be; h0.z = h0.z * ga + be; h0.w = h0.w * ga + be;
        h1.x = h1.x * ga + be; h1.y = h1.y * ga + be; h1.z = h1.z * ga + be; h1.w = h1.w * ga + be;
        *reinterpret_cast<float4*>(&Hs[hk][hn])     = h0;
        *reinterpret_cast<float4*>(&Hs[hk][hn + 4]) = h1;
        __syncthreads();
#pragma unroll
        for (int k = 0; k < 32; ++k) {
            const f32x4 av = *reinterpret_cast<const f32x4*>(&Hs[k][ty * 4]);
            const f32x4 bv = *reinterpret_cast<const f32x4*>(&WT[k][tx * 4]);
#pragma unroll
            for (int i = 0; i < 4; ++i)
#pragma unroll
                for (int j = 0; j < 4; ++j) acc[i][j] += av[i] * bv[j];
        }
        __syncthreads();
    }
    const bool isV = (o0 >= 512);
    const float scal = (o0 < 256) ? 0.0625f : 1.0f;
#pragma unroll
    for (int i = 0; i < 4; ++i)
#pragma unroll
        for (int j = 0; j < 4; ++j) {
            float val = (acc[i][j] + qkv_b[o0 + tx * 4 + j]) * scal;
            if (!isV) T[ty * 4 + i][tx * 4 + j] = f2bf(val);
            else      T[tx * 4 + j][ty * 4 + i] = f2bf(val);
        }
    __syncthreads();
    const int rr = t >> 2, cb = (t & 3) * 16;
    short8 s0 = *reinterpret_cast<short8*>(&T[rr][cb]);
    short8 s1 = *reinterpret_cast<short8*>(&T[rr][cb + 8]);
    u16* dst;
    if (o0 < 256)      dst = &Q[((size_t)b * 4096 + n0 + rr) * 256 + o0 + cb];
    else if (o0 < 512) dst = &K[((size_t)b * 4096 + n0 + rr) * 256 + (o0 - 256) + cb];
    else               dst = &V[((size_t)b * 256 + (o0 - 512) + rr) * 4096 + n0 + cb];
    *reinterpret_cast<short8*>(dst)     = s0;
    *reinterpret_cast<short8*>(dst + 8) = s1;
}

// ---------------- Kernel 3: flash attention, LDS-staged, split-KV ----------------
// Grid (16 qtiles, 4 splits, 4 batch); block = 512 thr = 8 waves, each wave 32 q-rows.
// Per tile (32 keys): K(16KB)+V(16KB) staged to LDS (dbuf) via global_load_lds, XOR-swizzled.
__global__ __launch_bounds__(512, 1) void k_flash(const u16* __restrict__ Qw, const u16* __restrict__ Kw,
                                                  const u16* __restrict__ Vw, u16* __restrict__ Opart,
                                                  float* __restrict__ ml) {
    __shared__ u16 Ks[2][8192];     // [32 keys][256 ch], rows 512B, swizzled
    __shared__ u16 Vs[2][8192];     // [256 ch][32 keys], rows 64B, pair-swizzled
    __shared__ u16 Ps[8][32][40];   // per-wave P staging
    const int b = blockIdx.z, sp = blockIdx.y;
    const int tid = threadIdx.x;
    const int w = tid >> 6, l = tid & 63;
    const int lr = l & 15, lg = l >> 4;
    const int qbase = blockIdx.x * 256 + w * 32;
    const int kb0 = sp * 1024;
    const size_t bN = (size_t)b * 4096;

    // ---- staging address setup (per thread) ----
    const int rK = tid >> 5;                                // + j*16
    const int kx = (((tid & 31) * 16) ^ ((rK & 7) << 4)) >> 1;
    const u16* srcK = Kw + (bN + kb0 + rK) * 256 + kx;
    const int vX = ((tid >> 3) & 7) << 4;
    const int lv = (tid * 16) ^ vX;                          // swizzled Lrc (round 0)
    const int rV = lv >> 6;                                  // + j*128
    const int cbV = lv & 63;
    const u16* srcV = Vw + ((size_t)b * 256 + rV) * 4096 + kb0 + (cbV >> 1);

#define STAGE(d, toff) { \
        const u16* sk_ = srcK + (size_t)(toff) * 8192; \
        gload16(sk_,             &Ks[d][tid * 8]); \
        gload16(sk_ + 16 * 256,  &Ks[d][4096 + tid * 8]); \
        const u16* sv_ = srcV + (toff) * 32; \
        gload16(sv_,             &Vs[d][tid * 8]); \
        gload16(sv_ + 128 * 4096, &Vs[d][4096 + tid * 8]); }

    // ---- compute-side swizzled offsets (per lane) ----
    const int c6 = (lr >> 2) & 1;                            // K: bit6 of XOR
    const int lgx = ((lg * 16) ^ ((lr & 3) << 4)) >> 1;      // K: bits4-5, elems
    int kofs[2];
#pragma unroll
    for (int n = 0; n < 2; ++n) kofs[n] = (n * 16 + lr) * 256 + lgx;
    const int vbase = ((lr * 64 + lg * 16) ^ (((lr >> 1) & 7) << 4)) >> 1;

    // ---- Q fragments ----
    short8 qf[2][8];
#pragma unroll
    for (int m = 0; m < 2; ++m)
#pragma unroll
        for (int cc = 0; cc < 8; ++cc)
            qf[m][cc] = *reinterpret_cast<const short8*>(&Qw[(bN + qbase + m * 16 + lr) * 256 + cc * 32 + lg * 8]);

    f32x4 Oa[2][16];
    float mr[2][4], lsum[2][4];
#pragma unroll
    for (int m = 0; m < 2; ++m) {
#pragma unroll
        for (int cs = 0; cs < 16; ++cs) Oa[m][cs] = f32x4{0.f, 0.f, 0.f, 0.f};
#pragma unroll
        for (int i = 0; i < 4; ++i) { mr[m][i] = -1e30f; lsum[m][i] = 0.f; }
    }

    STAGE(0, 0);
    for (int t = 0; t < 32; ++t) {
        const int d = t & 1;
        if (t < 31) {
            STAGE(d ^ 1, t + 1);
            asm volatile("s_waitcnt vmcnt(4)" ::: "memory");
        } else {
            asm volatile("s_waitcnt vmcnt(0)" ::: "memory");
        }
        __builtin_amdgcn_sched_barrier(0);
        __builtin_amdgcn_s_barrier();

        // ---- S = Q K^T ----
        f32x4 sc[2][2];
#pragma unroll
        for (int m = 0; m < 2; ++m)
#pragma unroll
            for (int n = 0; n < 2; ++n) sc[m][n] = f32x4{0.f, 0.f, 0.f, 0.f};
#pragma unroll
        for (int cc = 0; cc < 8; ++cc) {
            const int cb = ((cc ^ c6) << 5);
#pragma unroll
            for (int n = 0; n < 2; ++n) {
                short8 kf = *reinterpret_cast<const short8*>(&Ks[d][kofs[n] + cb]);
                sc[0][n] = __builtin_amdgcn_mfma_f32_16x16x32_bf16(qf[0][cc], kf, sc[0][n], 0, 0, 0);
                sc[1][n] = __builtin_amdgcn_mfma_f32_16x16x32_bf16(qf[1][cc], kf, sc[1][n], 0, 0, 0);
            }
        }
        // ---- online softmax ----
        float tmax[2][4];
        bool need = false;
#pragma unroll
        for (int m = 0; m < 2; ++m)
#pragma unroll
            for (int i = 0; i < 4; ++i) {
                float tm = fmaxf(sc[m][0][i], sc[m][1][i]);
                tm = fmaxf(tm, __shfl_xor(tm, 1));
                tm = fmaxf(tm, __shfl_xor(tm, 2));
                tm = fmaxf(tm, __shfl_xor(tm, 4));
                tm = fmaxf(tm, __shfl_xor(tm, 8));
                tmax[m][i] = tm;
                need = need || (tm > mr[m][i]);
            }
        if (__any(need)) {
#pragma unroll
            for (int m = 0; m < 2; ++m) {
                f32x4 al;
#pragma unroll
                for (int i = 0; i < 4; ++i) {
                    float mn = fmaxf(mr[m][i], tmax[m][i]);
                    al[i] = __expf(mr[m][i] - mn);
                    mr[m][i] = mn;
                    lsum[m][i] *= al[i];
                }
#pragma unroll
                for (int cs = 0; cs < 16; ++cs) Oa[m][cs] *= al;
            }
        }
#pragma unroll
        for (int m = 0; m < 2; ++m)
#pragma unroll
            for (int n = 0; n < 2; ++n)
#pragma unroll
                for (int i = 0; i < 4; ++i) {
                    float p = __expf(sc[m][n][i] - mr[m][i]);
                    lsum[m][i] += p;
                    Ps[w][m * 16 + lg * 4 + i][n * 16 + lr] = f2bf(p);
                }
        short8 pf[2];
#pragma unroll
        for (int m = 0; m < 2; ++m)
            pf[m] = *reinterpret_cast<const short8*>(&Ps[w][m * 16 + lr][lg * 8]);
        // ---- O += P V ----
#pragma unroll
        for (int cs = 0; cs < 16; ++cs) {
            short8 vf = *reinterpret_cast<const short8*>(&Vs[d][cs * 512 + vbase]);
            Oa[0][cs] = __builtin_amdgcn_mfma_f32_16x16x32_bf16(pf[0], vf, Oa[0][cs], 0, 0, 0);
            Oa[1][cs] = __builtin_amdgcn_mfma_f32_16x16x32_bf16(pf[1], vf, Oa[1][cs], 0, 0, 0);
        }
        __builtin_amdgcn_s_barrier();
        __builtin_amdgcn_sched_barrier(0);
    }
#undef STAGE

    // ---- epilogue: unnormalized partial O (bf16) + (m, l) per row ----
#pragma unroll
    for (int m = 0; m < 2; ++m)
#pragma unroll
        for (int i = 0; i < 4; ++i) {
            float ts = lsum[m][i];
            ts += __shfl_xor(ts, 1);
            ts += __shfl_xor(ts, 2);
            ts += __shfl_xor(ts, 4);
            ts += __shfl_xor(ts, 8);
            lsum[m][i] = ts;
        }
    const size_t obase = ((size_t)(b * 4 + sp) * 4096 + qbase);
#pragma unroll
    for (int m = 0; m < 2; ++m)
#pragma unroll
        for (int cs = 0; cs < 16; ++cs)
#pragma unroll
            for (int i = 0; i < 4; ++i)
                Opart[(obase + m * 16 + lg * 4 + i) * 256 + cs * 16 + lr] = f2bf(Oa[m][cs][i]);
    if (lr == 0) {
#pragma unroll
        for (int m = 0; m < 2; ++m)
#pragma unroll
            for (int i = 0; i < 4; ++i) {
                size_t r = obase + m * 16 + lg * 4 + i;
                ml[r * 2]     = mr[m][i];
                ml[r * 2 + 1] = lsum[m][i];
            }
    }
}

// ---------------- Kernel 3b: combine split-KV partials ----------------
__global__ __launch_bounds__(256) void k_comb(const u16* __restrict__ Opart, const float* __restrict__ ml,
                                              float* __restrict__ Ow) {
    const int row = blockIdx.x * 8 + (threadIdx.x >> 5);   // b*4096 + n
    const int b = row >> 12;
    const int c0 = (threadIdx.x & 31) * 8;
    const size_t rbase = (size_t)b * 4 * 4096 + (row & 4095);
    float ms[4], lsv[4];
#pragma unroll
    for (int s = 0; s < 4; ++s) {
        ms[s]  = ml[(rbase + (size_t)s * 4096) * 2];
        lsv[s] = ml[(rbase + (size_t)s * 4096) * 2 + 1];
    }
    float M = fmaxf(fmaxf(ms[0], ms[1]), fmaxf(ms[2], ms[3]));
    float W[4], L = 0.f;
#pragma unroll
    for (int s = 0; s < 4; ++s) { W[s] = __expf(ms[s] - M); L += W[s] * lsv[s]; }
    const float inv = 1.f / L;
    float o[8] = {};
#pragma unroll
    for (int s = 0; s < 4; ++s) {
        short8 v = *reinterpret_cast<const short8*>(&Opart[(rbase + (size_t)s * 4096) * 256 + c0]);
#pragma unroll
        for (int j = 0; j < 8; ++j) o[j] += W[s] * bf2f((u16)v[j]);
    }
    float4 r0, r1;
    r0.x = o[0] * inv; r0.y = o[1] * inv; r0.z = o[2] * inv; r0.w = o[3] * inv;
    r1.x = o[4] * inv; r1.y = o[5] * inv; r1.z = o[6] * inv; r1.w = o[7] * inv;
    float* dst = &Ow[(size_t)row * 256 + c0];
    *reinterpret_cast<float4*>(dst)     = r0;
    *reinterpret_cast<float4*>(dst + 4) = r1;
}

// ---------------- Kernel 4: proj 1x1 conv + bias + residual (fp32 GEMM) ----------------
__global__ __launch_bounds__(256) void k_proj(const float* __restrict__ Ow, const float* __restrict__ proj_w,
                                              const float* __restrict__ proj_b, const float* __restrict__ x,
                                              float* __restrict__ out) {
    __shared__ float WpT[32][72];
    __shared__ float OT[32][72];
    __shared__ float T3[64][68];
    const int b = blockIdx.z, c0 = blockIdx.y * 64, n0 = blockIdx.x * 64;
    const int t = threadIdx.x, tx = t & 15, ty = t >> 4;
    const int sr = t >> 2, skb = (t & 3) * 8;

    float acc[4][4] = {};
    for (int kc = 0; kc < 256; kc += 32) {
        const float* wp = &proj_w[(size_t)(c0 + sr) * 256 + kc + skb];
        float4 w0 = *reinterpret_cast<const float4*>(wp);
        float4 w1 = *reinterpret_cast<const float4*>(wp + 4);
        WpT[skb + 0][sr] = w0.x; WpT[skb + 1][sr] = w0.y; WpT[skb + 2][sr] = w0.z; WpT[skb + 3][sr] = w0.w;
        WpT[skb + 4][sr] = w1.x; WpT[skb + 5][sr] = w1.y; WpT[skb + 6][sr] = w1.z; WpT[skb + 7][sr] = w1.w;
        const float* op = &Ow[((size_t)b * 4096 + n0 + sr) * 256 + kc + skb];
        float4 o0v = *reinterpret_cast<const float4*>(op);
        float4 o1v = *reinterpret_cast<const float4*>(op + 4);
        OT[skb + 0][sr] = o0v.x; OT[skb + 1][sr] = o0v.y; OT[skb + 2][sr] = o0v.z; OT[skb + 3][sr] = o0v.w;
        OT[skb + 4][sr] = o1v.x; OT[skb + 5][sr] = o1v.y; OT[skb + 6][sr] = o1v.z; OT[skb + 7][sr] = o1v.w;
        __syncthreads();
#pragma unroll
        for (int k = 0; k < 32; ++k) {
            const f32x4 av = *reinterpret_cast<const f32x4*>(&WpT[k][ty * 4]);
            const f32x4 bv = *reinterpret_cast<const f32x4*>(&OT[k][tx * 4]);
#pragma unroll
            for (int i = 0; i < 4; ++i)
#pragma unroll
                for (int j = 0; j < 4; ++j) acc[i][j] += av[i] * bv[j];
        }
        __syncthreads();
    }
#pragma unroll
    for (int i = 0; i < 4; ++i)
#pragma unroll
        for (int j = 0; j < 4; ++j) T3[ty * 4 + i][tx * 4 + j] = acc[i][j];
    __syncthreads();
    const int cl = t >> 2, nb = (t & 3) * 16;
    const float pb = proj_b[c0 + cl];
    const size_t base = ((size_t)b * 256 + c0 + cl) * 4096 + n0 + nb;
#pragma unroll
    for (int q = 0; q < 16; q += 4) {
        float4 xv = *reinterpret_cast<const float4*>(&x[base + q]);
        float4 tv = *reinterpret_cast<float4*>(&T3[cl][nb + q]);
        float4 r;
        r.x = xv.x + tv.x + pb; r.y = xv.y + tv.y + pb;
        r.z = xv.z + tv.z + pb; r.w = xv.w + tv.w + pb;
        *reinterpret_cast<float4*>(&out[base + q]) = r;
    }
}

extern "C" void kernel_launch(void* const* d_in, const int* in_sizes, int n_in,
                              void* d_out, int out_size, void* d_ws, size_t ws_size,
                              hipStream_t stream) {
    const float* x      = (const float*)d_in[0];
    const float* gngam  = (const float*)d_in[1];
    const float* gnbeta = (const float*)d_in[2];
    const float* qkv_w  = (const float*)d_in[3];
    const float* qkv_b  = (const float*)d_in[4];
    const float* proj_w = (const float*)d_in[5];
    const float* proj_b = (const float*)d_in[6];
    float* out = (float*)d_out;

    char* wsb = (char*)d_ws;
    float* stats = (float*)wsb;                                    // 64 floats
    u16* Qws   = (u16*)(wsb + 1024);                               // 8MB  (B,N,C) bf16 pre-scaled
    u16* Kws   = Qws + (size_t)4 * 4096 * 256;                     // 8MB  (B,N,C) bf16
    u16* Vws   = Kws + (size_t)4 * 4096 * 256;                     // 8MB  (B,C,N) bf16
    u16* Opart = Vws + (size_t)4 * 4096 * 256;                     // 32MB (B,S,N,C) bf16 unnormalized
    float* ml  = (float*)(Opart + (size_t)16 * 4096 * 256);        // 512KB (B,S,N,2) f32
    float* Ows = ml + (size_t)16 * 4096 * 2;                       // 16MB (B,N,C) f32

    k_gnstats<<<32, 256, 0, stream>>>(x, stats);
    k_qkv<<<dim3(64, 12, 4), 256, 0, stream>>>(x, gngam, gnbeta, qkv_w, qkv_b, stats, Qws, Kws, Vws);
    k_flash<<<dim3(16, 4, 4), 512, 0, stream>>>(Qws, Kws, Vws, Opart, ml);
    k_comb<<<2048, 256, 0, stream>>>(Opart, ml, Ows);
    k_proj<<<dim3(64, 4, 4), 256, 0, stream>>>(Ows, proj_w, proj_b, x, out);
}

// Round 3
// 245.562 us; speedup vs baseline: 3.0997x; 1.2892x over previous
//
#include <hip/hip_runtime.h>
#include <hip/hip_bf16.h>

typedef unsigned short u16;
typedef unsigned int u32;
typedef __attribute__((ext_vector_type(8))) short short8;
typedef __attribute__((ext_vector_type(4))) float f32x4;

static __device__ __forceinline__ u16 f2bf(float f) {
    union { float f; unsigned u; } a; a.f = f;
    unsigned u = a.u;
    u += 0x7FFFu + ((u >> 16) & 1u);   // RNE; inputs are finite
    return (u16)(u >> 16);
}
static __device__ __forceinline__ float bf2f(u16 h) {
    union { u32 u; float f; } a; a.u = ((u32)h) << 16; return a.f;
}
static __device__ __forceinline__ void gload16(const u16* g, u16* l) {
    __builtin_amdgcn_global_load_lds((const __attribute__((address_space(1))) u32*)(const void*)g,
                                     (__attribute__((address_space(3))) u32*)(void*)l, 16, 0, 0);
}

// ---------------- Kernel 1: GroupNorm statistics (mu, rstd) per (b, g) ----------------
__global__ __launch_bounds__(256) void k_gnstats(const float* __restrict__ x, float* __restrict__ stats) {
    const int bg = blockIdx.x;
    const float* p = x + (size_t)bg * (32 * 4096);
    const int t = threadIdx.x;
    float s = 0.f, ss = 0.f;
    for (int i = t * 4; i < 32 * 4096; i += 256 * 4) {
        float4 v = *reinterpret_cast<const float4*>(p + i);
        s  += v.x + v.y + v.z + v.w;
        ss += v.x * v.x + v.y * v.y + v.z * v.z + v.w * v.w;
    }
    for (int off = 1; off < 64; off <<= 1) { s += __shfl_xor(s, off); ss += __shfl_xor(ss, off); }
    __shared__ float ls[4], lss[4];
    if ((t & 63) == 0) { ls[t >> 6] = s; lss[t >> 6] = ss; }
    __syncthreads();
    if (t == 0) {
        float S  = ls[0] + ls[1] + ls[2] + ls[3];
        float SS = lss[0] + lss[1] + lss[2] + lss[3];
        const float inv = 1.f / (32.f * 4096.f);
        float mu  = S * inv;
        float var = SS * inv - mu * mu;
        stats[bg * 2]     = mu;
        stats[bg * 2 + 1] = rsqrtf(var + 1e-5f);
    }
}

// ---------------- Kernel 1b: weights fp32 -> bf16 ----------------
__global__ __launch_bounds__(256) void k_wconv(const float* __restrict__ qw, const float* __restrict__ pw,
                                               u16* __restrict__ q2, u16* __restrict__ p2) {
    const int i = (blockIdx.x * 256 + threadIdx.x) * 4;
    const float* src; u16* dst;
    if (i < 196608) { src = qw + i; dst = q2 + i; }
    else            { src = pw + (i - 196608); dst = p2 + (i - 196608); }
    float4 v = *reinterpret_cast<const float4*>(src);
    u16 o[4] = { f2bf(v.x), f2bf(v.y), f2bf(v.z), f2bf(v.w) };
    *reinterpret_cast<uint2*>(dst) = *reinterpret_cast<uint2*>(o);
}

// ---------------- Kernel 1c: GN-normalize + transpose -> Hbf (B,N,C) bf16 ----------------
__global__ __launch_bounds__(256) void k_norm(const float* __restrict__ x, const float* __restrict__ gamma,
                                              const float* __restrict__ beta, const float* __restrict__ stats,
                                              u16* __restrict__ H) {
    __shared__ u16 T[64][72];   // [c_local][n_local]
    const int b = blockIdx.z, c0 = blockIdx.y * 64, n0 = blockIdx.x * 64;
    const int t = threadIdx.x;
    const int cl = t >> 2, nb = (t & 3) * 16;
    const int c = c0 + cl;
    const float mu = stats[(b * 8 + (c >> 5)) * 2];
    const float rstd = stats[(b * 8 + (c >> 5)) * 2 + 1];
    const float ga = gamma[c] * rstd, be = beta[c] - mu * ga;
    const float* xp = &x[((size_t)b * 256 + c) * 4096 + n0 + nb];
#pragma unroll
    for (int j = 0; j < 16; j += 4) {
        float4 v = *reinterpret_cast<const float4*>(xp + j);
        T[cl][nb + j + 0] = f2bf(v.x * ga + be);
        T[cl][nb + j + 1] = f2bf(v.y * ga + be);
        T[cl][nb + j + 2] = f2bf(v.z * ga + be);
        T[cl][nb + j + 3] = f2bf(v.w * ga + be);
    }
    __syncthreads();
    const int nl = t >> 2, cb = (t & 3) * 16;
    short8 s0, s1;
#pragma unroll
    for (int j = 0; j < 8; ++j) { s0[j] = (short)T[cb + j][nl]; s1[j] = (short)T[cb + 8 + j][nl]; }
    u16* dst = &H[((size_t)b * 4096 + n0 + nl) * 256 + c0 + cb];
    *reinterpret_cast<short8*>(dst)     = s0;
    *reinterpret_cast<short8*>(dst + 8) = s1;
}

// ---------------- Kernel 2: QKV as bf16 MFMA GEMM ----------------
// out[b][o][n] = sum_c W[o][c] * H[b][n][c] ; block = 4 waves, tile 128n x 64o
// Writes: Q (B,N,C) scaled by 1/16*log2(e) ; K (B,N,C) ; V (B,C,N)   all bf16
__global__ __launch_bounds__(256) void k_qkv(const u16* __restrict__ H, const u16* __restrict__ W2,
                                             const float* __restrict__ qkv_b,
                                             u16* __restrict__ Q, u16* __restrict__ K, u16* __restrict__ V) {
    __shared__ u16 T[9216];   // Q/K: [128][72] ; V: [64][144]
    const int b = blockIdx.z, o0 = blockIdx.x * 64, nb0 = blockIdx.y * 128;
    const int t = threadIdx.x, w = t >> 6, l = t & 63, lr = l & 15, lg = l >> 4;
    const size_t bN = (size_t)b * 4096;
    f32x4 acc[2][4];
#pragma unroll
    for (int m = 0; m < 2; ++m)
#pragma unroll
        for (int nf = 0; nf < 4; ++nf) acc[m][nf] = f32x4{0.f, 0.f, 0.f, 0.f};
    const u16* A0 = &H[(bN + nb0 + w * 32 + lr) * 256];
    const u16* A1 = A0 + 16 * 256;
#pragma unroll
    for (int cc = 0; cc < 8; ++cc) {
        short8 af0 = *reinterpret_cast<const short8*>(A0 + cc * 32 + lg * 8);
        short8 af1 = *reinterpret_cast<const short8*>(A1 + cc * 32 + lg * 8);
#pragma unroll
        for (int nf = 0; nf < 4; ++nf) {
            short8 bf = *reinterpret_cast<const short8*>(&W2[(size_t)(o0 + nf * 16 + lr) * 256 + cc * 32 + lg * 8]);
            acc[0][nf] = __builtin_amdgcn_mfma_f32_16x16x32_bf16(af0, bf, acc[0][nf], 0, 0, 0);
            acc[1][nf] = __builtin_amdgcn_mfma_f32_16x16x32_bf16(af1, bf, acc[1][nf], 0, 0, 0);
        }
    }
    const int og = o0 >> 8;   // 0=Q, 1=K, 2=V
    const float scal = (og == 0) ? 0.0625f * 1.44269504f : 1.0f;   // fold C^-0.5 * log2(e) into Q
    float bias[4];
#pragma unroll
    for (int nf = 0; nf < 4; ++nf) bias[nf] = qkv_b[o0 + nf * 16 + lr];
    if (og < 2) {
#pragma unroll
        for (int m = 0; m < 2; ++m)
#pragma unroll
            for (int nf = 0; nf < 4; ++nf)
#pragma unroll
                for (int i = 0; i < 4; ++i)
                    T[(w * 32 + m * 16 + lg * 4 + i) * 72 + nf * 16 + lr] = f2bf((acc[m][nf][i] + bias[nf]) * scal);
        __syncthreads();
        const int rl = t >> 1, half = (t & 1) * 32;
        u16* dst = (og == 0 ? Q : K) + (bN + nb0 + rl) * 256 + (o0 & 255) + half;
#pragma unroll
        for (int j = 0; j < 4; ++j)
            *reinterpret_cast<short8*>(dst + j * 8) = *reinterpret_cast<short8*>(&T[rl * 72 + half + j * 8]);
    } else {
#pragma unroll
        for (int m = 0; m < 2; ++m)
#pragma unroll
            for (int nf = 0; nf < 4; ++nf)
#pragma unroll
                for (int i = 0; i < 4; ++i)
                    T[(nf * 16 + lr) * 144 + w * 32 + m * 16 + lg * 4 + i] = f2bf(acc[m][nf][i] + bias[nf]);
        __syncthreads();
        const int ol = t >> 2, nbl = (t & 3) * 32;
        u16* dst = V + ((size_t)b * 256 + (o0 - 512) + ol) * 4096 + nb0 + nbl;
#pragma unroll
        for (int j = 0; j < 4; ++j)
            *reinterpret_cast<short8*>(dst + j * 8) = *reinterpret_cast<short8*>(&T[ol * 144 + nbl + j * 8]);
    }
}

// ---------------- Kernel 3: flash attention (exp2 domain, defer-max, 2 blocks/CU) ----------------
// Grid (32 qtiles, 4 splits, 4 b); block = 256 thr = 4 waves, wave owns 32 q-rows.
__global__ __launch_bounds__(256, 2) void k_flash(const u16* __restrict__ Qw, const u16* __restrict__ Kw,
                                                  const u16* __restrict__ Vw, u16* __restrict__ Opart,
                                                  float* __restrict__ ml) {
    __shared__ u16 Ks[2][8192];        // [32 keys][256 ch] swizzled, 16KB each
    __shared__ u16 Vs[2][8192];        // [256 ch][32 keys] linear, 16KB each
    __shared__ u16 Ps[4][2][16][40];   // per-wave P staging
    const int b = blockIdx.z, sp = blockIdx.y;
    const int tid = threadIdx.x;
    const int w = tid >> 6, l = tid & 63;
    const int lr = l & 15, lg = l >> 4;
    const int qbase = blockIdx.x * 128 + w * 32;
    const int kb0 = sp * 1024;
    const size_t bN = (size_t)b * 4096;

    // staging sources (pre-swizzled K, linear V)
    const u16* srcK = Kw + (bN + kb0 + (tid >> 5)) * 256 + (((tid & 31) * 8) ^ ((tid >> 5) * 8));
    const u16* srcV = Vw + ((size_t)b * 256 + (tid >> 2)) * 4096 + kb0 + (tid & 3) * 8;

#define STAGE(d, toff) { \
        const u16* sk_ = srcK + (size_t)(toff) * 8192; \
        const u16* sv_ = srcV + (toff) * 32; \
        gload16(sk_,              Ks[d] + tid * 8); \
        gload16(sk_ + 2048,       Ks[d] + 2048 + tid * 8); \
        gload16(sk_ + 4096,       Ks[d] + 4096 + tid * 8); \
        gload16(sk_ + 6144,       Ks[d] + 6144 + tid * 8); \
        gload16(sv_,              Vs[d] + tid * 8); \
        gload16(sv_ + 64 * 4096,  Vs[d] + 2048 + tid * 8); \
        gload16(sv_ + 128 * 4096, Vs[d] + 4096 + tid * 8); \
        gload16(sv_ + 192 * 4096, Vs[d] + 6144 + tid * 8); }

    // compute-side offsets
    const int c6 = (lr >> 2) & 1;
    int kofs[2];
#pragma unroll
    for (int n = 0; n < 2; ++n) kofs[n] = (n * 16 + lr) * 256 + ((lg * 8) ^ ((lr & 3) * 8));
    const int vofs = lr * 32 + lg * 8;

    // Q fragments (global, L2-resident)
    short8 qf[2][8];
#pragma unroll
    for (int m = 0; m < 2; ++m)
#pragma unroll
        for (int cc = 0; cc < 8; ++cc)
            qf[m][cc] = *reinterpret_cast<const short8*>(&Qw[(bN + qbase + m * 16 + lr) * 256 + cc * 32 + lg * 8]);

    f32x4 Oa[2][16];
    float mr[2][4], lsum[2][4];
#pragma unroll
    for (int m = 0; m < 2; ++m) {
#pragma unroll
        for (int cs = 0; cs < 16; ++cs) Oa[m][cs] = f32x4{0.f, 0.f, 0.f, 0.f};
#pragma unroll
        for (int i = 0; i < 4; ++i) { mr[m][i] = -1e30f; lsum[m][i] = 0.f; }
    }

    STAGE(0, 0);
    for (int kt = 0; kt < 32; ++kt) {
        const int d = kt & 1;
        if (kt < 31) {
            STAGE(d ^ 1, kt + 1);
            asm volatile("s_waitcnt vmcnt(8)" ::: "memory");
        } else {
            asm volatile("s_waitcnt vmcnt(0)" ::: "memory");
        }
        __builtin_amdgcn_sched_barrier(0);
        __builtin_amdgcn_s_barrier();

        // ---- S' = (QK^T) * log2e-scale (folded into Q) ----
        f32x4 sc[2][2];
#pragma unroll
        for (int m = 0; m < 2; ++m)
#pragma unroll
            for (int n = 0; n < 2; ++n) sc[m][n] = f32x4{0.f, 0.f, 0.f, 0.f};
        __builtin_amdgcn_s_setprio(1);
#pragma unroll
        for (int cc = 0; cc < 8; ++cc) {
            const int cb = ((cc ^ c6) << 5);
#pragma unroll
            for (int n = 0; n < 2; ++n) {
                short8 kf = *reinterpret_cast<const short8*>(&Ks[d][kofs[n] + cb]);
                sc[0][n] = __builtin_amdgcn_mfma_f32_16x16x32_bf16(qf[0][cc], kf, sc[0][n], 0, 0, 0);
                sc[1][n] = __builtin_amdgcn_mfma_f32_16x16x32_bf16(qf[1][cc], kf, sc[1][n], 0, 0, 0);
            }
        }
        __builtin_amdgcn_s_setprio(0);

        // ---- online softmax (base-2, defer-max threshold 8) ----
        float tmax[2][4];
        bool need = false;
#pragma unroll
        for (int m = 0; m < 2; ++m)
#pragma unroll
            for (int i = 0; i < 4; ++i) {
                float tm = fmaxf(sc[m][0][i], sc[m][1][i]);
                tm = fmaxf(tm, __shfl_xor(tm, 1));
                tm = fmaxf(tm, __shfl_xor(tm, 2));
                tm = fmaxf(tm, __shfl_xor(tm, 4));
                tm = fmaxf(tm, __shfl_xor(tm, 8));
                tmax[m][i] = tm;
                need = need || (tm > mr[m][i] + 8.f);
            }
        if (__any(need)) {
#pragma unroll
            for (int m = 0; m < 2; ++m) {
                f32x4 al;
#pragma unroll
                for (int i = 0; i < 4; ++i) {
                    float mn = fmaxf(mr[m][i], tmax[m][i]);
                    al[i] = exp2f(mr[m][i] - mn);
                    mr[m][i] = mn;
                    lsum[m][i] *= al[i];
                }
#pragma unroll
                for (int cs = 0; cs < 16; ++cs) Oa[m][cs] *= al;
            }
        }
#pragma unroll
        for (int m = 0; m < 2; ++m)
#pragma unroll
            for (int n = 0; n < 2; ++n)
#pragma unroll
                for (int i = 0; i < 4; ++i) {
                    float p = exp2f(sc[m][n][i] - mr[m][i]);
                    lsum[m][i] += p;
                    Ps[w][m][lg * 4 + i][n * 16 + lr] = f2bf(p);
                }
        asm volatile("s_waitcnt lgkmcnt(0)" ::: "memory");
        __builtin_amdgcn_sched_barrier(0);
        short8 pf[2];
#pragma unroll
        for (int m = 0; m < 2; ++m)
            pf[m] = *reinterpret_cast<const short8*>(&Ps[w][m][lr][lg * 8]);
        // ---- O += P V ----
        __builtin_amdgcn_s_setprio(1);
#pragma unroll
        for (int cs = 0; cs < 16; ++cs) {
            short8 vf = *reinterpret_cast<const short8*>(&Vs[d][cs * 512 + vofs]);
            Oa[0][cs] = __builtin_amdgcn_mfma_f32_16x16x32_bf16(pf[0], vf, Oa[0][cs], 0, 0, 0);
            Oa[1][cs] = __builtin_amdgcn_mfma_f32_16x16x32_bf16(pf[1], vf, Oa[1][cs], 0, 0, 0);
        }
        __builtin_amdgcn_s_setprio(0);
        __builtin_amdgcn_s_barrier();
    }
#undef STAGE

    // ---- epilogue: unnormalized partial O (bf16) + (m, l) per row ----
#pragma unroll
    for (int m = 0; m < 2; ++m)
#pragma unroll
        for (int i = 0; i < 4; ++i) {
            float ts = lsum[m][i];
            ts += __shfl_xor(ts, 1);
            ts += __shfl_xor(ts, 2);
            ts += __shfl_xor(ts, 4);
            ts += __shfl_xor(ts, 8);
            lsum[m][i] = ts;
        }
    const size_t obase = ((size_t)(b * 4 + sp) * 4096 + qbase);
#pragma unroll
    for (int m = 0; m < 2; ++m)
#pragma unroll
        for (int cs = 0; cs < 16; ++cs)
#pragma unroll
            for (int i = 0; i < 4; ++i)
                Opart[(obase + m * 16 + lg * 4 + i) * 256 + cs * 16 + lr] = f2bf(Oa[m][cs][i]);
    if (lr == 0) {
#pragma unroll
        for (int m = 0; m < 2; ++m)
#pragma unroll
            for (int i = 0; i < 4; ++i) {
                size_t r = obase + m * 16 + lg * 4 + i;
                ml[r * 2]     = mr[m][i];
                ml[r * 2 + 1] = lsum[m][i];
            }
    }
}

// ---------------- Kernel 3b: combine split-KV partials -> Obf (B,N,C) bf16 ----------------
__global__ __launch_bounds__(256) void k_comb(const u16* __restrict__ Opart, const float* __restrict__ ml,
                                              u16* __restrict__ Obf) {
    const int row = blockIdx.x * 8 + (threadIdx.x >> 5);   // b*4096 + n
    const int b = row >> 12;
    const int c0 = (threadIdx.x & 31) * 8;
    const size_t rbase = (size_t)b * 4 * 4096 + (row & 4095);
    float ms[4], lsv[4];
#pragma unroll
    for (int s = 0; s < 4; ++s) {
        ms[s]  = ml[(rbase + (size_t)s * 4096) * 2];
        lsv[s] = ml[(rbase + (size_t)s * 4096) * 2 + 1];
    }
    float M = fmaxf(fmaxf(ms[0], ms[1]), fmaxf(ms[2], ms[3]));
    float W[4], L = 0.f;
#pragma unroll
    for (int s = 0; s < 4; ++s) { W[s] = exp2f(ms[s] - M); L += W[s] * lsv[s]; }
    const float inv = 1.f / L;
    float o[8] = {};
#pragma unroll
    for (int s = 0; s < 4; ++s) {
        short8 v = *reinterpret_cast<const short8*>(&Opart[(rbase + (size_t)s * 4096) * 256 + c0]);
#pragma unroll
        for (int j = 0; j < 8; ++j) o[j] += W[s] * bf2f((u16)v[j]);
    }
    short8 r;
#pragma unroll
    for (int j = 0; j < 8; ++j) r[j] = (short)f2bf(o[j] * inv);
    *reinterpret_cast<short8*>(&Obf[(size_t)row * 256 + c0]) = r;
}

// ---------------- Kernel 4: proj as bf16 MFMA GEMM + bias + residual ----------------
// out[b][c][n] = x[b][c][n] + proj_b[c] + sum_k Wp[c][k] * O[b][n][k]
__global__ __launch_bounds__(256) void k_proj(const u16* __restrict__ O, const u16* __restrict__ Wp,
                                              const float* __restrict__ proj_b, const float* __restrict__ x,
                                              float* __restrict__ out) {
    __shared__ float T[64][132];   // [c_local][n_local] f32
    const int b = blockIdx.z, c0 = blockIdx.x * 64, nb0 = blockIdx.y * 128;
    const int t = threadIdx.x, w = t >> 6, l = t & 63, lr = l & 15, lg = l >> 4;
    const size_t bN = (size_t)b * 4096;
    f32x4 acc[2][4];
#pragma unroll
    for (int m = 0; m < 2; ++m)
#pragma unroll
        for (int nf = 0; nf < 4; ++nf) acc[m][nf] = f32x4{0.f, 0.f, 0.f, 0.f};
    const u16* A0 = &O[(bN + nb0 + w * 32 + lr) * 256];
    const u16* A1 = A0 + 16 * 256;
#pragma unroll
    for (int cc = 0; cc < 8; ++cc) {
        short8 af0 = *reinterpret_cast<const short8*>(A0 + cc * 32 + lg * 8);
        short8 af1 = *reinterpret_cast<const short8*>(A1 + cc * 32 + lg * 8);
#pragma unroll
        for (int nf = 0; nf < 4; ++nf) {
            short8 bf = *reinterpret_cast<const short8*>(&Wp[(size_t)(c0 + nf * 16 + lr) * 256 + cc * 32 + lg * 8]);
            acc[0][nf] = __builtin_amdgcn_mfma_f32_16x16x32_bf16(af0, bf, acc[0][nf], 0, 0, 0);
            acc[1][nf] = __builtin_amdgcn_mfma_f32_16x16x32_bf16(af1, bf, acc[1][nf], 0, 0, 0);
        }
    }
#pragma unroll
    for (int m = 0; m < 2; ++m)
#pragma unroll
        for (int nf = 0; nf < 4; ++nf)
#pragma unroll
            for (int i = 0; i < 4; ++i)
                T[nf * 16 + lr][w * 32 + m * 16 + lg * 4 + i] = acc[m][nf][i];
    __syncthreads();
    const int cl = t >> 2, nbl = (t & 3) * 32;
    const float pb = proj_b[c0 + cl];
    const size_t base = ((size_t)b * 256 + c0 + cl) * 4096 + nb0 + nbl;
#pragma unroll
    for (int j = 0; j < 32; j += 4) {
        float4 xv = *reinterpret_cast<const float4*>(&x[base + j]);
        float4 r;
        r.x = xv.x + T[cl][nbl + j + 0] + pb;
        r.y = xv.y + T[cl][nbl + j + 1] + pb;
        r.z = xv.z + T[cl][nbl + j + 2] + pb;
        r.w = xv.w + T[cl][nbl + j + 3] + pb;
        *reinterpret_cast<float4*>(&out[base + j]) = r;
    }
}

extern "C" void kernel_launch(void* const* d_in, const int* in_sizes, int n_in,
                              void* d_out, int out_size, void* d_ws, size_t ws_size,
                              hipStream_t stream) {
    const float* x      = (const float*)d_in[0];
    const float* gngam  = (const float*)d_in[1];
    const float* gnbeta = (const float*)d_in[2];
    const float* qkv_w  = (const float*)d_in[3];
    const float* qkv_b  = (const float*)d_in[4];
    const float* proj_w = (const float*)d_in[5];
    const float* proj_b = (const float*)d_in[6];
    float* out = (float*)d_out;

    char* wsb = (char*)d_ws;
    float* stats = (float*)wsb;                       // 1 KB
    u16* Hbf   = (u16*)(wsb + 1024);                  // 8 MB (B,N,C)
    u16* Qws   = Hbf + 4194304;                       // 8 MB (B,N,C) pre-scaled
    u16* Kws   = Qws + 4194304;                       // 8 MB (B,N,C)
    u16* Vws   = Kws + 4194304;                       // 8 MB (B,C,N)
    u16* W2q   = Vws + 4194304;                       // 384 KB
    u16* W2p   = W2q + 196608;                        // 128 KB
    u16* Opart = W2p + 65536;                         // 32 MB (B,S,N,C) unnormalized
    float* ml  = (float*)(Opart + 16777216);          // 512 KB (B,S,N,2)
    u16* Obf   = (u16*)(ml + 131072);                 // 8 MB (B,N,C)

    k_gnstats<<<32, 256, 0, stream>>>(x, stats);
    k_wconv<<<256, 256, 0, stream>>>(qkv_w, proj_w, W2q, W2p);
    k_norm<<<dim3(64, 4, 4), 256, 0, stream>>>(x, gngam, gnbeta, stats, Hbf);
    k_qkv<<<dim3(12, 32, 4), 256, 0, stream>>>(Hbf, W2q, qkv_b, Qws, Kws, Vws);
    k_flash<<<dim3(32, 4, 4), 256, 0, stream>>>(Qws, Kws, Vws, Opart, ml);
    k_comb<<<2048, 256, 0, stream>>>(Opart, ml, Obf);
    k_proj<<<dim3(4, 32, 4), 256, 0, stream>>>(Obf, W2p, proj_b, x, out);
}

// Round 4
// 201.016 us; speedup vs baseline: 3.7866x; 1.2216x over previous
//
#include <hip/hip_runtime.h>
#include <hip/hip_bf16.h>

typedef unsigned short u16;
typedef unsigned int u32;
typedef __attribute__((ext_vector_type(8))) short short8;
typedef __attribute__((ext_vector_type(4))) short short4v;
typedef __attribute__((ext_vector_type(4))) float f32x4;

static __device__ __forceinline__ u16 f2bf(float f) {
    union { float f; unsigned u; } a; a.f = f;
    unsigned u = a.u;
    u += 0x7FFFu + ((u >> 16) & 1u);   // RNE; inputs are finite
    return (u16)(u >> 16);
}
static __device__ __forceinline__ float bf2f(u16 h) {
    union { u32 u; float f; } a; a.u = ((u32)h) << 16; return a.f;
}
static __device__ __forceinline__ void gload16(const u16* g, u16* l) {
    __builtin_amdgcn_global_load_lds((const __attribute__((address_space(1))) u32*)(const void*)g,
                                     (__attribute__((address_space(3))) u32*)(void*)l, 16, 0, 0);
}

// ---------------- Kernel 1: GroupNorm statistics (mu, rstd) per (b, g) ----------------
__global__ __launch_bounds__(256) void k_gnstats(const float* __restrict__ x, float* __restrict__ stats) {
    const int bg = blockIdx.x;
    const float* p = x + (size_t)bg * (32 * 4096);
    const int t = threadIdx.x;
    float s = 0.f, ss = 0.f;
    for (int i = t * 4; i < 32 * 4096; i += 256 * 4) {
        float4 v = *reinterpret_cast<const float4*>(p + i);
        s  += v.x + v.y + v.z + v.w;
        ss += v.x * v.x + v.y * v.y + v.z * v.z + v.w * v.w;
    }
    for (int off = 1; off < 64; off <<= 1) { s += __shfl_xor(s, off); ss += __shfl_xor(ss, off); }
    __shared__ float ls[4], lss[4];
    if ((t & 63) == 0) { ls[t >> 6] = s; lss[t >> 6] = ss; }
    __syncthreads();
    if (t == 0) {
        float S  = ls[0] + ls[1] + ls[2] + ls[3];
        float SS = lss[0] + lss[1] + lss[2] + lss[3];
        const float inv = 1.f / (32.f * 4096.f);
        float mu  = S * inv;
        float var = SS * inv - mu * mu;
        stats[bg * 2]     = mu;
        stats[bg * 2 + 1] = rsqrtf(var + 1e-5f);
    }
}

// ---------------- Kernel 1b: weights fp32 -> bf16 ----------------
__global__ __launch_bounds__(256) void k_wconv(const float* __restrict__ qw, const float* __restrict__ pw,
                                               u16* __restrict__ q2, u16* __restrict__ p2) {
    const int i = (blockIdx.x * 256 + threadIdx.x) * 4;
    const float* src; u16* dst;
    if (i < 196608) { src = qw + i; dst = q2 + i; }
    else            { src = pw + (i - 196608); dst = p2 + (i - 196608); }
    float4 v = *reinterpret_cast<const float4*>(src);
    u16 o[4] = { f2bf(v.x), f2bf(v.y), f2bf(v.z), f2bf(v.w) };
    *reinterpret_cast<uint2*>(dst) = *reinterpret_cast<uint2*>(o);
}

// ---------------- Kernel 1c: GN-normalize + transpose -> Hbf (B,N,C) bf16 ----------------
__global__ __launch_bounds__(256) void k_norm(const float* __restrict__ x, const float* __restrict__ gamma,
                                              const float* __restrict__ beta, const float* __restrict__ stats,
                                              u16* __restrict__ H) {
    __shared__ u16 T[64][72];   // [c_local][n_local]
    const int b = blockIdx.z, c0 = blockIdx.y * 64, n0 = blockIdx.x * 64;
    const int t = threadIdx.x;
    const int cl = t >> 2, nb = (t & 3) * 16;
    const int c = c0 + cl;
    const float mu = stats[(b * 8 + (c >> 5)) * 2];
    const float rstd = stats[(b * 8 + (c >> 5)) * 2 + 1];
    const float ga = gamma[c] * rstd, be = beta[c] - mu * ga;
    const float* xp = &x[((size_t)b * 256 + c) * 4096 + n0 + nb];
#pragma unroll
    for (int j = 0; j < 16; j += 4) {
        float4 v = *reinterpret_cast<const float4*>(xp + j);
        T[cl][nb + j + 0] = f2bf(v.x * ga + be);
        T[cl][nb + j + 1] = f2bf(v.y * ga + be);
        T[cl][nb + j + 2] = f2bf(v.z * ga + be);
        T[cl][nb + j + 3] = f2bf(v.w * ga + be);
    }
    __syncthreads();
    const int nl = t >> 2, cb = (t & 3) * 16;
    short8 s0, s1;
#pragma unroll
    for (int j = 0; j < 8; ++j) { s0[j] = (short)T[cb + j][nl]; s1[j] = (short)T[cb + 8 + j][nl]; }
    u16* dst = &H[((size_t)b * 4096 + n0 + nl) * 256 + c0 + cb];
    *reinterpret_cast<short8*>(dst)     = s0;
    *reinterpret_cast<short8*>(dst + 8) = s1;
}

// ---------------- Kernel 2: QKV as bf16 MFMA GEMM ----------------
// Writes: Q (B,N,C) scaled by 1/16*log2(e) ; K (B,N,C) ; V (B,C,N) with per-32-key-block
// XOR-swizzle: key-group g (4 keys) stored at slot g ^ ((ch>>1)&7).
__global__ __launch_bounds__(256) void k_qkv(const u16* __restrict__ H, const u16* __restrict__ W2,
                                             const float* __restrict__ qkv_b,
                                             u16* __restrict__ Q, u16* __restrict__ K, u16* __restrict__ V) {
    __shared__ u16 T[9216];   // Q/K: [128][72] ; V: [64][144]
    const int b = blockIdx.z, o0 = blockIdx.x * 64, nb0 = blockIdx.y * 128;
    const int t = threadIdx.x, w = t >> 6, l = t & 63, lr = l & 15, lg = l >> 4;
    const size_t bN = (size_t)b * 4096;
    f32x4 acc[2][4];
#pragma unroll
    for (int m = 0; m < 2; ++m)
#pragma unroll
        for (int nf = 0; nf < 4; ++nf) acc[m][nf] = f32x4{0.f, 0.f, 0.f, 0.f};
    const u16* A0 = &H[(bN + nb0 + w * 32 + lr) * 256];
    const u16* A1 = A0 + 16 * 256;
#pragma unroll
    for (int cc = 0; cc < 8; ++cc) {
        short8 af0 = *reinterpret_cast<const short8*>(A0 + cc * 32 + lg * 8);
        short8 af1 = *reinterpret_cast<const short8*>(A1 + cc * 32 + lg * 8);
#pragma unroll
        for (int nf = 0; nf < 4; ++nf) {
            short8 bf = *reinterpret_cast<const short8*>(&W2[(size_t)(o0 + nf * 16 + lr) * 256 + cc * 32 + lg * 8]);
            acc[0][nf] = __builtin_amdgcn_mfma_f32_16x16x32_bf16(af0, bf, acc[0][nf], 0, 0, 0);
            acc[1][nf] = __builtin_amdgcn_mfma_f32_16x16x32_bf16(af1, bf, acc[1][nf], 0, 0, 0);
        }
    }
    const int og = o0 >> 8;   // 0=Q, 1=K, 2=V
    const float scal = (og == 0) ? 0.0625f * 1.44269504f : 1.0f;   // fold C^-0.5 * log2(e) into Q
    float bias[4];
#pragma unroll
    for (int nf = 0; nf < 4; ++nf) bias[nf] = qkv_b[o0 + nf * 16 + lr];
    if (og < 2) {
#pragma unroll
        for (int m = 0; m < 2; ++m)
#pragma unroll
            for (int nf = 0; nf < 4; ++nf)
#pragma unroll
                for (int i = 0; i < 4; ++i)
                    T[(w * 32 + m * 16 + lg * 4 + i) * 72 + nf * 16 + lr] = f2bf((acc[m][nf][i] + bias[nf]) * scal);
        __syncthreads();
        const int rl = t >> 1, half = (t & 1) * 32;
        u16* dst = (og == 0 ? Q : K) + (bN + nb0 + rl) * 256 + (o0 & 255) + half;
#pragma unroll
        for (int j = 0; j < 4; ++j)
            *reinterpret_cast<short8*>(dst + j * 8) = *reinterpret_cast<short8*>(&T[rl * 72 + half + j * 8]);
    } else {
#pragma unroll
        for (int m = 0; m < 2; ++m)
#pragma unroll
            for (int nf = 0; nf < 4; ++nf)
#pragma unroll
                for (int i = 0; i < 4; ++i)
                    T[(nf * 16 + lr) * 144 + w * 32 + m * 16 + lg * 4 + i] = f2bf(acc[m][nf][i] + bias[nf]);
        __syncthreads();
        const int ol = t >> 2, nbl = (t & 3) * 32;
        const int s_ = (ol >> 1) & 7;                    // == (global_ch>>1)&7 since o0%64==0
        u16* dst = V + ((size_t)b * 256 + (o0 - 512) + ol) * 4096 + nb0 + nbl;
#pragma unroll
        for (int j = 0; j < 4; ++j) {
            short8 vv = *reinterpret_cast<short8*>(&T[ol * 144 + nbl + j * 8]);
            short8 ov;
            if (s_ & 1) ov = short8{vv[4], vv[5], vv[6], vv[7], vv[0], vv[1], vv[2], vv[3]};
            else        ov = vv;
            *reinterpret_cast<short8*>(dst + (((2 * j) ^ (s_ & 6)) * 4)) = ov;
        }
    }
}

// ---------------- Kernel 3: flash attention, swapped-QK, register-resident P ----------------
// Grid (32 qtiles, 4 splits, 4 b); block = 256 thr = 4 waves, wave owns 32 q-rows.
// S = mfma(K, Q): lane holds S[key = lg*4+i + 16n][query = lr + 16m]  -> row reduce is
// in-register + 2 shuffles. P (bf16, packed pf[j]=(n=j>>2,i=j&3)) is a valid MFMA A-operand
// under k-bijection pi(lg,j) = (j>>2)*16 + lg*4 + (j&3); V fragments loaded with same k-map.
__global__ __launch_bounds__(256, 2) void k_flash(const u16* __restrict__ Qw, const u16* __restrict__ Kw,
                                                  const u16* __restrict__ Vw, u16* __restrict__ Opart,
                                                  float* __restrict__ ml) {
    __shared__ u16 Ks[2][8192];     // [32 keys][256 ch] swizzled rows (512B)
    __shared__ u16 Vs[2][8192];     // [256 ch][32 keys] slot-swizzled rows (64B)
    const int b = blockIdx.z, sp = blockIdx.y;
    const int tid = threadIdx.x;
    const int w = tid >> 6, l = tid & 63;
    const int lr = l & 15, lg = l >> 4;
    const int qbase = blockIdx.x * 128 + w * 32;
    const int kb0 = sp * 1024;
    const size_t bN = (size_t)b * 4096;

    // staging sources (pre-swizzled K source; V pre-swizzled in global)
    const u16* srcK = Kw + (bN + kb0 + (tid >> 5)) * 256 + (((tid & 31) * 8) ^ ((tid >> 5) * 8));
    const u16* srcV = Vw + ((size_t)b * 256 + (tid >> 2)) * 4096 + kb0 + (tid & 3) * 8;

#define STAGE(d, toff) { \
        const u16* sk_ = srcK + (size_t)(toff) * 8192; \
        const u16* sv_ = srcV + (toff) * 32; \
        gload16(sk_,              Ks[d] + tid * 8); \
        gload16(sk_ + 2048,       Ks[d] + 2048 + tid * 8); \
        gload16(sk_ + 4096,       Ks[d] + 4096 + tid * 8); \
        gload16(sk_ + 6144,       Ks[d] + 6144 + tid * 8); \
        gload16(sv_,              Vs[d] + tid * 8); \
        gload16(sv_ + 64 * 4096,  Vs[d] + 2048 + tid * 8); \
        gload16(sv_ + 128 * 4096, Vs[d] + 4096 + tid * 8); \
        gload16(sv_ + 192 * 4096, Vs[d] + 6144 + tid * 8); }

    // K read offsets (swizzle-resolved)
    const int c6 = (lr >> 2) & 1;
    int kofs[2];
#pragma unroll
    for (int n = 0; n < 2; ++n) kofs[n] = (n * 16 + lr) * 256 + ((lg * 8) ^ ((lr & 3) * 8));
    // V read offsets: slot A = lg ^ (lr>>1), slot B = A ^ 4 (elements: *4)
    const int vslotA = ((lg ^ (lr >> 1)) * 4);
    const int vslotB = vslotA ^ 16;

    // Q fragments (B-operand layout; L2-resident)
    short8 qf[2][8];
#pragma unroll
    for (int m = 0; m < 2; ++m)
#pragma unroll
        for (int cc = 0; cc < 8; ++cc)
            qf[m][cc] = *reinterpret_cast<const short8*>(&Qw[(bN + qbase + m * 16 + lr) * 256 + cc * 32 + lg * 8]);

    f32x4 Oa[2][16];
    float mr[2], lsum[2];
#pragma unroll
    for (int m = 0; m < 2; ++m) {
#pragma unroll
        for (int cs = 0; cs < 16; ++cs) Oa[m][cs] = f32x4{0.f, 0.f, 0.f, 0.f};
        mr[m] = -1e30f; lsum[m] = 0.f;
    }

    STAGE(0, 0);
    for (int kt = 0; kt < 32; ++kt) {
        const int d = kt & 1;
        if (kt < 31) {
            STAGE(d ^ 1, kt + 1);
            asm volatile("s_waitcnt vmcnt(8)" ::: "memory");
        } else {
            asm volatile("s_waitcnt vmcnt(0)" ::: "memory");
        }
        __builtin_amdgcn_sched_barrier(0);
        __builtin_amdgcn_s_barrier();

        // ---- S = mfma(K, Q): rows = keys, cols = queries ----
        f32x4 sc[2][2];   // [m][n]
#pragma unroll
        for (int m = 0; m < 2; ++m)
#pragma unroll
            for (int n = 0; n < 2; ++n) sc[m][n] = f32x4{0.f, 0.f, 0.f, 0.f};
        __builtin_amdgcn_s_setprio(1);
#pragma unroll
        for (int cc = 0; cc < 8; ++cc) {
            const int cb = ((cc ^ c6) << 5);
            short8 kf0 = *reinterpret_cast<const short8*>(&Ks[d][kofs[0] + cb]);
            short8 kf1 = *reinterpret_cast<const short8*>(&Ks[d][kofs[1] + cb]);
            sc[0][0] = __builtin_amdgcn_mfma_f32_16x16x32_bf16(kf0, qf[0][cc], sc[0][0], 0, 0, 0);
            sc[0][1] = __builtin_amdgcn_mfma_f32_16x16x32_bf16(kf1, qf[0][cc], sc[0][1], 0, 0, 0);
            sc[1][0] = __builtin_amdgcn_mfma_f32_16x16x32_bf16(kf0, qf[1][cc], sc[1][0], 0, 0, 0);
            sc[1][1] = __builtin_amdgcn_mfma_f32_16x16x32_bf16(kf1, qf[1][cc], sc[1][1], 0, 0, 0);
        }
        __builtin_amdgcn_s_setprio(0);

        // ---- online softmax (per-query lane-local; 2 shuffles per m) ----
        float tmax[2];
        bool need = false;
#pragma unroll
        for (int m = 0; m < 2; ++m) {
            float tm = fmaxf(fmaxf(fmaxf(sc[m][0][0], sc[m][0][1]), fmaxf(sc[m][0][2], sc[m][0][3])),
                             fmaxf(fmaxf(sc[m][1][0], sc[m][1][1]), fmaxf(sc[m][1][2], sc[m][1][3])));
            tm = fmaxf(tm, __shfl_xor(tm, 16));
            tm = fmaxf(tm, __shfl_xor(tm, 32));
            tmax[m] = tm;
            need = need || (tm > mr[m] + 8.f);   // defer-max threshold (T13)
        }
        if (__any(need)) {
            float av[2][4];
#pragma unroll
            for (int m = 0; m < 2; ++m) {
                float mn = fmaxf(mr[m], tmax[m]);
                float al = exp2f(mr[m] - mn);
                mr[m] = mn;
                lsum[m] *= al;
#pragma unroll
                for (int i = 0; i < 4; ++i) av[m][i] = __shfl(al, lg * 4 + i);  // to q=lg*4+i space
            }
#pragma unroll
            for (int m = 0; m < 2; ++m)
#pragma unroll
                for (int cs = 0; cs < 16; ++cs)
#pragma unroll
                    for (int i = 0; i < 4; ++i) Oa[m][cs][i] *= av[m][i];
        }
        // ---- P = exp2(S - m), pack to bf16 A-operand in-register ----
        short8 pf[2];
#pragma unroll
        for (int m = 0; m < 2; ++m) {
            float la = 0.f;
#pragma unroll
            for (int n = 0; n < 2; ++n)
#pragma unroll
                for (int i = 0; i < 4; ++i) {
                    float p = exp2f(sc[m][n][i] - mr[m]);
                    la += p;
                    pf[m][n * 4 + i] = (short)f2bf(p);
                }
            lsum[m] += la;
        }
        // ---- O += P V (V fragment with matching k-map) ----
        __builtin_amdgcn_s_setprio(1);
#pragma unroll
        for (int cs = 0; cs < 16; ++cs) {
            const int base = (cs * 16 + lr) * 32;
            short4v lo = *reinterpret_cast<const short4v*>(&Vs[d][base + vslotA]);
            short4v hi = *reinterpret_cast<const short4v*>(&Vs[d][base + vslotB]);
            short8 vf = __builtin_shufflevector(lo, hi, 0, 1, 2, 3, 4, 5, 6, 7);
            Oa[0][cs] = __builtin_amdgcn_mfma_f32_16x16x32_bf16(pf[0], vf, Oa[0][cs], 0, 0, 0);
            Oa[1][cs] = __builtin_amdgcn_mfma_f32_16x16x32_bf16(pf[1], vf, Oa[1][cs], 0, 0, 0);
        }
        __builtin_amdgcn_s_setprio(0);
        __builtin_amdgcn_s_barrier();
    }
#undef STAGE

    // ---- epilogue: unnormalized partial O (bf16) + (m, l) per row ----
    float lt[2];
#pragma unroll
    for (int m = 0; m < 2; ++m) {
        float ts = lsum[m];
        ts += __shfl_xor(ts, 16);
        ts += __shfl_xor(ts, 32);
        lt[m] = ts;
    }
    const size_t obase = ((size_t)(b * 4 + sp) * 4096 + qbase);
#pragma unroll
    for (int m = 0; m < 2; ++m)
#pragma unroll
        for (int cs = 0; cs < 16; ++cs)
#pragma unroll
            for (int i = 0; i < 4; ++i)
                Opart[(obase + m * 16 + lg * 4 + i) * 256 + cs * 16 + lr] = f2bf(Oa[m][cs][i]);
    if (lg == 0) {
#pragma unroll
        for (int m = 0; m < 2; ++m) {
            size_t r = obase + m * 16 + lr;
            ml[r * 2]     = mr[m];
            ml[r * 2 + 1] = lt[m];
        }
    }
}

// ---------------- Kernel 3b: combine split-KV partials -> Obf (B,N,C) bf16 ----------------
__global__ __launch_bounds__(256) void k_comb(const u16* __restrict__ Opart, const float* __restrict__ ml,
                                              u16* __restrict__ Obf) {
    const int row = blockIdx.x * 8 + (threadIdx.x >> 5);   // b*4096 + n
    const int b = row >> 12;
    const int c0 = (threadIdx.x & 31) * 8;
    const size_t rbase = (size_t)b * 4 * 4096 + (row & 4095);
    float ms[4], lsv[4];
#pragma unroll
    for (int s = 0; s < 4; ++s) {
        ms[s]  = ml[(rbase + (size_t)s * 4096) * 2];
        lsv[s] = ml[(rbase + (size_t)s * 4096) * 2 + 1];
    }
    float M = fmaxf(fmaxf(ms[0], ms[1]), fmaxf(ms[2], ms[3]));
    float W[4], L = 0.f;
#pragma unroll
    for (int s = 0; s < 4; ++s) { W[s] = exp2f(ms[s] - M); L += W[s] * lsv[s]; }
    const float inv = 1.f / L;
    float o[8] = {};
#pragma unroll
    for (int s = 0; s < 4; ++s) {
        short8 v = *reinterpret_cast<const short8*>(&Opart[(rbase + (size_t)s * 4096) * 256 + c0]);
#pragma unroll
        for (int j = 0; j < 8; ++j) o[j] += W[s] * bf2f((u16)v[j]);
    }
    short8 r;
#pragma unroll
    for (int j = 0; j < 8; ++j) r[j] = (short)f2bf(o[j] * inv);
    *reinterpret_cast<short8*>(&Obf[(size_t)row * 256 + c0]) = r;
}

// ---------------- Kernel 4: proj as bf16 MFMA GEMM + bias + residual ----------------
__global__ __launch_bounds__(256) void k_proj(const u16* __restrict__ O, const u16* __restrict__ Wp,
                                              const float* __restrict__ proj_b, const float* __restrict__ x,
                                              float* __restrict__ out) {
    __shared__ float T[64][132];   // [c_local][n_local] f32
    const int b = blockIdx.z, c0 = blockIdx.x * 64, nb0 = blockIdx.y * 128;
    const int t = threadIdx.x, w = t >> 6, l = t & 63, lr = l & 15, lg = l >> 4;
    const size_t bN = (size_t)b * 4096;
    f32x4 acc[2][4];
#pragma unroll
    for (int m = 0; m < 2; ++m)
#pragma unroll
        for (int nf = 0; nf < 4; ++nf) acc[m][nf] = f32x4{0.f, 0.f, 0.f, 0.f};
    const u16* A0 = &O[(bN + nb0 + w * 32 + lr) * 256];
    const u16* A1 = A0 + 16 * 256;
#pragma unroll
    for (int cc = 0; cc < 8; ++cc) {
        short8 af0 = *reinterpret_cast<const short8*>(A0 + cc * 32 + lg * 8);
        short8 af1 = *reinterpret_cast<const short8*>(A1 + cc * 32 + lg * 8);
#pragma unroll
        for (int nf = 0; nf < 4; ++nf) {
            short8 bf = *reinterpret_cast<const short8*>(&Wp[(size_t)(c0 + nf * 16 + lr) * 256 + cc * 32 + lg * 8]);
            acc[0][nf] = __builtin_amdgcn_mfma_f32_16x16x32_bf16(af0, bf, acc[0][nf], 0, 0, 0);
            acc[1][nf] = __builtin_amdgcn_mfma_f32_16x16x32_bf16(af1, bf, acc[1][nf], 0, 0, 0);
        }
    }
#pragma unroll
    for (int m = 0; m < 2; ++m)
#pragma unroll
        for (int nf = 0; nf < 4; ++nf)
#pragma unroll
            for (int i = 0; i < 4; ++i)
                T[nf * 16 + lr][w * 32 + m * 16 + lg * 4 + i] = acc[m][nf][i];
    __syncthreads();
    const int cl = t >> 2, nbl = (t & 3) * 32;
    const float pb = proj_b[c0 + cl];
    const size_t base = ((size_t)b * 256 + c0 + cl) * 4096 + nb0 + nbl;
#pragma unroll
    for (int j = 0; j < 32; j += 4) {
        float4 xv = *reinterpret_cast<const float4*>(&x[base + j]);
        float4 r;
        r.x = xv.x + T[cl][nbl + j + 0] + pb;
        r.y = xv.y + T[cl][nbl + j + 1] + pb;
        r.z = xv.z + T[cl][nbl + j + 2] + pb;
        r.w = xv.w + T[cl][nbl + j + 3] + pb;
        *reinterpret_cast<float4*>(&out[base + j]) = r;
    }
}

extern "C" void kernel_launch(void* const* d_in, const int* in_sizes, int n_in,
                              void* d_out, int out_size, void* d_ws, size_t ws_size,
                              hipStream_t stream) {
    const float* x      = (const float*)d_in[0];
    const float* gngam  = (const float*)d_in[1];
    const float* gnbeta = (const float*)d_in[2];
    const float* qkv_w  = (const float*)d_in[3];
    const float* qkv_b  = (const float*)d_in[4];
    const float* proj_w = (const float*)d_in[5];
    const float* proj_b = (const float*)d_in[6];
    float* out = (float*)d_out;

    char* wsb = (char*)d_ws;
    float* stats = (float*)wsb;                       // 1 KB
    u16* Hbf   = (u16*)(wsb + 1024);                  // 8 MB (B,N,C)
    u16* Qws   = Hbf + 4194304;                       // 8 MB (B,N,C) pre-scaled
    u16* Kws   = Qws + 4194304;                       // 8 MB (B,N,C)
    u16* Vws   = Kws + 4194304;                       // 8 MB (B,C,N) slot-swizzled
    u16* W2q   = Vws + 4194304;                       // 384 KB
    u16* W2p   = W2q + 196608;                        // 128 KB
    u16* Opart = W2p + 65536;                         // 32 MB (B,S,N,C) unnormalized
    float* ml  = (float*)(Opart + 16777216);          // 512 KB (B,S,N,2)
    u16* Obf   = (u16*)(ml + 131072);                 // 8 MB (B,N,C)

    k_gnstats<<<32, 256, 0, stream>>>(x, stats);
    k_wconv<<<256, 256, 0, stream>>>(qkv_w, proj_w, W2q, W2p);
    k_norm<<<dim3(64, 4, 4), 256, 0, stream>>>(x, gngam, gnbeta, stats, Hbf);
    k_qkv<<<dim3(12, 32, 4), 256, 0, stream>>>(Hbf, W2q, qkv_b, Qws, Kws, Vws);
    k_flash<<<dim3(32, 4, 4), 256, 0, stream>>>(Qws, Kws, Vws, Opart, ml);
    k_comb<<<2048, 256, 0, stream>>>(Opart, ml, Obf);
    k_proj<<<dim3(4, 32, 4), 256, 0, stream>>>(Obf, W2p, proj_b, x, out);
}